// Round 5
// baseline (2357.065 us; speedup 1.0000x reference)
//
#include <hip/hip_runtime.h>

#define B_ 16
#define S_ 4096
#define D_ 256
#define H_ 256

typedef _Float16 h2 __attribute__((ext_vector_type(2)));
typedef _Float16 h8 __attribute__((ext_vector_type(8)));
typedef float f4 __attribute__((ext_vector_type(4)));

static __device__ __forceinline__ float fdot2f(h2 a, h2 b, float c) {
    return __builtin_amdgcn_fdot2(a, b, c, false);
}

// pure-VALU cross-lane via DPP quad_perm; ctrl must be ICE
template <int CTRL>
static __device__ __forceinline__ float dpp_qp(float v) {
    int r = __builtin_amdgcn_update_dpp(0, __float_as_int(v), CTRL, 0xF, 0xF, true);
    return __int_as_float(r);
}
#define DPP_XOR1 0xB1   // quad_perm [1,0,3,2]
#define DPP_XOR2 0x4E   // quad_perm [2,3,0,1]

// swizzled f16-index for h element i in a 256-entry LDS buffer:
// slice s=i>>6 (128B block), chunk r=(i>>3)&7 (16B), XOR-placed so the 4
// distinct addresses of a quad's distributed read hit disjoint bank quads.
static __device__ __forceinline__ int swz(int i) {
    const int s = i >> 6, r = (i >> 3) & 7, e = i & 7;
    return 64 * s + 8 * ((r + 2 * s) & 7) + e;
}

// Kernel 1: xp[r][h] = sum_d x[r][d] * Wx[d][h] + bias[h], written into d_out.
__global__ __launch_bounds__(256) void xproj_kernel(
    const float* __restrict__ x, const float* __restrict__ Wx,
    const float* __restrict__ bias, float* __restrict__ out)
{
    __shared__ float xs[32 * 256];
    const int tid = threadIdx.x;
    const long long row0 = (long long)blockIdx.x * 32;

    {
        const f4* __restrict__ xg = (const f4*)(x + row0 * D_);
        f4* xsv = (f4*)xs;
        #pragma unroll
        for (int k = 0; k < 8; ++k)
            xsv[tid + k * 256] = xg[tid + k * 256];
    }
    __syncthreads();

    const int j = tid;
    float acc[32];
    const float bj = bias[j];
    #pragma unroll
    for (int r = 0; r < 32; ++r) acc[r] = bj;

    for (int d4 = 0; d4 < D_ / 4; ++d4) {
        const float w0 = Wx[(d4 * 4 + 0) * H_ + j];
        const float w1 = Wx[(d4 * 4 + 1) * H_ + j];
        const float w2 = Wx[(d4 * 4 + 2) * H_ + j];
        const float w3 = Wx[(d4 * 4 + 3) * H_ + j];
        #pragma unroll
        for (int r = 0; r < 32; ++r) {
            f4 xv = *(const f4*)&xs[r * 256 + d4 * 4];
            acc[r] = fmaf(xv.x, w0, acc[r]);
            acc[r] = fmaf(xv.y, w1, acc[r]);
            acc[r] = fmaf(xv.z, w2, acc[r]);
            acc[r] = fmaf(xv.w, w3, acc[r]);
        }
    }
    #pragma unroll
    for (int r = 0; r < 32; ++r)
        out[(row0 + r) * H_ + j] = acc[r];
}

// Kernel 2: sequential scan, one block (CU) per batch, 1024 threads
// (16 waves = 4 waves/SIMD for latency hiding).
// Thread t: output j = t>>2, i-slice s = t&3 (64 i's, 32 dot2, 4 chains).
// h read distributed from swizzled LDS (8 x b128, quad-disjoint banks),
// quad all-reduce via DPP xor1+xor2 (pure VALU). Lane s==0 owns the xp
// prefetch ring, the global store, and the h publish.
__global__ __launch_bounds__(1024, 1) void scan_kernel(
    const float* __restrict__ Wh, const float* __restrict__ state0,
    float* __restrict__ out)
{
    __shared__ __align__(16) _Float16 hbuf[2][H_];
    const int tid = threadIdx.x;
    const int s = tid & 3;          // i-slice
    const int j = tid >> 2;         // owned output column
    const int b = blockIdx.x;
    const bool owner = (s == 0);

    // W[i][j] for i in [64s, 64s+64), packed as h2 i-pairs: 32 VGPRs
    h2 w[32];
    #pragma unroll
    for (int ii = 0; ii < 32; ++ii) {
        const int i = 64 * s + 2 * ii;
        h2 p;
        p[0] = (_Float16)Wh[(long long)i * H_ + j];
        p[1] = (_Float16)Wh[(long long)(i + 1) * H_ + j];
        w[ii] = p;
    }

    if (owner) hbuf[0][swz(j)] = (_Float16)state0[b * H_ + j];

    float* __restrict__ outb = out + (long long)b * S_ * H_;

    // xp prefetch ring, distance 4 (owner lanes only; static idx via unroll)
    float xr[4] = {0.f, 0.f, 0.f, 0.f};
    if (owner) {
        #pragma unroll
        for (int k = 0; k < 4; ++k)
            xr[k] = outb[(long long)k * H_ + j];
    }
    __syncthreads();

    #pragma unroll 4
    for (int st = 0; st < S_; ++st) {
        const int p = st & 1;
        const _Float16* hb = hbuf[p];

        // slice s: chunk r lives at f16-pos 64s + 8*((r+2s)&7)
        h8 hv[8];
        #pragma unroll
        for (int r = 0; r < 8; ++r)
            hv[r] = *(const h8*)&hb[64 * s + 8 * ((r + 2 * s) & 7)];

        float a0 = 0.f, a1 = 0.f, a2 = 0.f, a3 = 0.f;
        #pragma unroll
        for (int r = 0; r < 8; ++r) {
            union { h8 v; h2 pr[4]; } u;
            u.v = hv[r];
            a0 = fdot2f(u.pr[0], w[4 * r + 0], a0);
            a1 = fdot2f(u.pr[1], w[4 * r + 1], a1);
            a2 = fdot2f(u.pr[2], w[4 * r + 2], a2);
            a3 = fdot2f(u.pr[3], w[4 * r + 3], a3);
        }
        float v = (a0 + a2) + (a1 + a3);
        // quad all-reduce (pure VALU DPP butterfly)
        v += dpp_qp<DPP_XOR1>(v);
        v += dpp_qp<DPP_XOR2>(v);

        const float pre = v + xr[st & 3];
        const float e = __builtin_amdgcn_exp2f(pre * 2.8853900817779268f);
        const float hn = fmaf(-2.f, __builtin_amdgcn_rcpf(e + 1.f), 1.f);

        if (owner) {
            outb[(long long)st * H_ + j] = hn;     // fire-and-forget store
            hbuf[p ^ 1][swz(j)] = (_Float16)hn;    // publish h for t+1
            const int nt = st + 4;
            xr[st & 3] = (nt < S_) ? outb[(long long)nt * H_ + j] : 0.f;
        }
        __syncthreads();
    }
}

extern "C" void kernel_launch(void* const* d_in, const int* in_sizes, int n_in,
                              void* d_out, int out_size, void* d_ws, size_t ws_size,
                              hipStream_t stream) {
    const float* x  = (const float*)d_in[0];   // [B,S,D]
    const float* s0 = (const float*)d_in[1];   // [B,H]
    const float* Wx = (const float*)d_in[2];   // [D,H]
    const float* Wh = (const float*)d_in[3];   // [H,H]
    const float* bv = (const float*)d_in[4];   // [H]
    float* out = (float*)d_out;                // [B,S,H]

    xproj_kernel<<<dim3((B_ * S_) / 32), dim3(256), 0, stream>>>(x, Wx, bv, out);
    scan_kernel<<<dim3(B_), dim3(1024), 0, stream>>>(Wh, s0, out);
}

// Round 6
// 1951.794 us; speedup vs baseline: 1.2076x; 1.2076x over previous
//
#include <hip/hip_runtime.h>

#define B_ 16
#define S_ 4096
#define D_ 256
#define H_ 256

typedef _Float16 h2 __attribute__((ext_vector_type(2)));
typedef _Float16 h8 __attribute__((ext_vector_type(8)));
typedef float f4 __attribute__((ext_vector_type(4)));

static __device__ __forceinline__ float fdot2f(h2 a, h2 b, float c) {
    return __builtin_amdgcn_fdot2(a, b, c, false);
}

// pure-VALU cross-lane via DPP; ctrl must be ICE
template <int CTRL>
static __device__ __forceinline__ float dpp_mv(float v) {
    int r = __builtin_amdgcn_update_dpp(0, __float_as_int(v), CTRL, 0xF, 0xF, true);
    return __int_as_float(r);
}
#define DPP_XOR1 0xB1    // quad_perm [1,0,3,2]    -> lane ^ 1
#define DPP_XOR2 0x4E    // quad_perm [2,3,0,1]    -> lane ^ 2
#define DPP_XOR8 0x128   // row_ror:8 (16-lane row) -> lane ^ 8

// LDS h layout: element i = 32*sl + 8*r + e lives at f16-pos 64*r + 8*sl + e.
// A wave's read of chunk r (8 slices) covers one full 128B stripe: conflict-free.
static __device__ __forceinline__ int hpos(int i) {
    const int sl = i >> 5, r = (i >> 3) & 3, e = i & 7;
    return 64 * r + 8 * sl + e;
}

// Kernel 1: xp[row][h] = sum_d x[row][d] * Wx[d][h] + bias[h], into d_out.
__global__ __launch_bounds__(256) void xproj_kernel(
    const float* __restrict__ x, const float* __restrict__ Wx,
    const float* __restrict__ bias, float* __restrict__ out)
{
    __shared__ float xs[32 * 256];
    const int tid = threadIdx.x;
    const long long row0 = (long long)blockIdx.x * 32;

    {
        const f4* __restrict__ xg = (const f4*)(x + row0 * D_);
        f4* xsv = (f4*)xs;
        #pragma unroll
        for (int k = 0; k < 8; ++k)
            xsv[tid + k * 256] = xg[tid + k * 256];
    }
    __syncthreads();

    const int j = tid;
    float acc[32];
    const float bj = bias[j];
    #pragma unroll
    for (int r = 0; r < 32; ++r) acc[r] = bj;

    for (int d4 = 0; d4 < D_ / 4; ++d4) {
        const float w0 = Wx[(d4 * 4 + 0) * H_ + j];
        const float w1 = Wx[(d4 * 4 + 1) * H_ + j];
        const float w2 = Wx[(d4 * 4 + 2) * H_ + j];
        const float w3 = Wx[(d4 * 4 + 3) * H_ + j];
        #pragma unroll
        for (int r = 0; r < 32; ++r) {
            f4 xv = *(const f4*)&xs[r * 256 + d4 * 4];
            acc[r] = fmaf(xv.x, w0, acc[r]);
            acc[r] = fmaf(xv.y, w1, acc[r]);
            acc[r] = fmaf(xv.z, w2, acc[r]);
            acc[r] = fmaf(xv.w, w3, acc[r]);
        }
    }
    #pragma unroll
    for (int r = 0; r < 32; ++r)
        out[(row0 + r) * H_ + j] = acc[r];
}

// Kernel 2: sequential scan, one block (CU) per batch, 512 threads
// (8 waves = 2 waves/SIMD).
// Thread t: slice sl = bits{0,1,3} of t (8 slices x 32 i's), j-group
// g = bits{2,4..8} (4 outputs j=4g..4g+3). Each thread: 4 b128 h-reads
// (G=4 reuse), 64 dot2. 8-way reduce = pure VALU DPP (xor1, xor2, xor8).
// Owner lane (bit3==0, j = 4g + (t&3)) does xp ring, store, h publish.
__global__ __launch_bounds__(512, 1) void scan_kernel(
    const float* __restrict__ Wh, const float* __restrict__ state0,
    float* __restrict__ out)
{
    __shared__ __align__(16) _Float16 hbuf[2][H_];
    const int t = threadIdx.x;
    const int sl = (t & 3) | ((t >> 1) & 4);        // slice 0..7
    const int g  = ((t >> 2) & 1) | ((t >> 4) << 1); // j-group 0..63
    const int b = blockIdx.x;
    const bool o1 = (sl & 1) != 0;
    const bool o2 = (sl & 2) != 0;
    const bool owner = (t & 8) == 0;
    const int j_own = 4 * g + (t & 3);

    // W[i][j] for i in [32*sl, 32*sl+32), j in [4g, 4g+4): 64 h2 regs
    h2 w[4][16];
    #pragma unroll
    for (int jj = 0; jj < 4; ++jj) {
        const int j = 4 * g + jj;
        #pragma unroll
        for (int ii = 0; ii < 16; ++ii) {
            const int i = 32 * sl + 2 * ii;
            h2 p;
            p[0] = (_Float16)Wh[(long long)i * H_ + j];
            p[1] = (_Float16)Wh[(long long)(i + 1) * H_ + j];
            w[jj][ii] = p;
        }
    }

    if (owner) hbuf[0][hpos(j_own)] = (_Float16)state0[b * H_ + j_own];

    float* __restrict__ outb = out + (long long)b * S_ * H_;

    // xp prefetch ring, distance 4 (owner lanes only)
    float xr[4] = {0.f, 0.f, 0.f, 0.f};
    if (owner) {
        #pragma unroll
        for (int k = 0; k < 4; ++k)
            xr[k] = outb[(long long)k * H_ + j_own];
    }
    __syncthreads();

    #pragma unroll 4
    for (int st = 0; st < S_; ++st) {
        const int p = st & 1;
        const _Float16* hb = hbuf[p];

        // 4 x b128: chunk r of slice sl at f16-pos 64r + 8sl
        h8 hv[4];
        #pragma unroll
        for (int r = 0; r < 4; ++r)
            hv[r] = *(const h8*)&hb[64 * r + 8 * sl];

        float a0 = 0.f, a1 = 0.f, a2 = 0.f, a3 = 0.f;
        #pragma unroll
        for (int r = 0; r < 4; ++r) {
            union { h8 v; h2 q[4]; } u;
            u.v = hv[r];
            #pragma unroll
            for (int m = 0; m < 4; ++m) {
                const int ii = 4 * r + m;
                a0 = fdot2f(u.q[m], w[0][ii], a0);
                a1 = fdot2f(u.q[m], w[1][ii], a1);
                a2 = fdot2f(u.q[m], w[2][ii], a2);
                a3 = fdot2f(u.q[m], w[3][ii], a3);
            }
        }

        // 8-way reduce-scatter over slices (pure VALU DPP)
        // stage 1 (lane^1): keep jj with (jj&1)==(sl&1)
        float vA = o1 ? a1 : a0;
        float vB = o1 ? a3 : a2;
        float sA = o1 ? a0 : a1;
        float sB = o1 ? a2 : a3;
        vA += dpp_mv<DPP_XOR1>(sA);
        vB += dpp_mv<DPP_XOR1>(sB);
        // stage 2 (lane^2): keep jj with (jj&2)==(sl&2)
        float v   = o2 ? vB : vA;
        float snd = o2 ? vA : vB;
        v += dpp_mv<DPP_XOR2>(snd);
        // stage 3 (lane^8): all-reduce (j duplicated in bit3 partners)
        v += dpp_mv<DPP_XOR8>(v);
        // v = full dot for j = 4g + (t&3)

        const float pre = v + xr[st & 3];
        const float e = __builtin_amdgcn_exp2f(pre * 2.8853900817779268f);
        const float hn = fmaf(-2.f, __builtin_amdgcn_rcpf(e + 1.f), 1.f);

        if (owner) {
            outb[(long long)st * H_ + j_own] = hn;   // coalesced 32/wave
            hbuf[p ^ 1][hpos(j_own)] = (_Float16)hn; // publish h for t+1
            const int nt = st + 4;
            xr[st & 3] = (nt < S_) ? outb[(long long)nt * H_ + j_own] : 0.f;
        }
        __syncthreads();
    }
}

extern "C" void kernel_launch(void* const* d_in, const int* in_sizes, int n_in,
                              void* d_out, int out_size, void* d_ws, size_t ws_size,
                              hipStream_t stream) {
    const float* x  = (const float*)d_in[0];   // [B,S,D]
    const float* s0 = (const float*)d_in[1];   // [B,H]
    const float* Wx = (const float*)d_in[2];   // [D,H]
    const float* Wh = (const float*)d_in[3];   // [H,H]
    const float* bv = (const float*)d_in[4];   // [H]
    float* out = (float*)d_out;                // [B,S,H]

    xproj_kernel<<<dim3((B_ * S_) / 32), dim3(256), 0, stream>>>(x, Wx, bv, out);
    scan_kernel<<<dim3(B_), dim3(512), 0, stream>>>(Wh, s0, out);
}